// Round 10
// baseline (940.020 us; speedup 1.0000x reference)
//
#include <hip/hip_runtime.h>
#include <math.h>

// Problem constants (fixed by setup_inputs: B=8, UPD=32, PPD=64)
#define H      256
#define NH     8
#define DH     32
#define FFDIM  1024
#define L1     128      // DEPTH*UNIT_LEN
#define B1     512      // B*PPD
#define L2     512      // UPD*UNIT_LEN
#define B2     8        // nb
#define N1     (L1*B1)  // 65536
#define N2     (L2*B2)  // 4096

typedef unsigned short u16;
typedef unsigned short ushort4_t __attribute__((ext_vector_type(4)));
typedef unsigned short ushort8_t __attribute__((ext_vector_type(8)));
typedef short          short8_t  __attribute__((ext_vector_type(8)));
typedef float          f32x4     __attribute__((ext_vector_type(4)));

__device__ __forceinline__ float bf2f(u16 u) {
    union { unsigned int i; float f; } v; v.i = ((unsigned int)u) << 16; return v.f;
}
__device__ __forceinline__ u16 f2bf(float f) {
    union { float f; unsigned int i; } v; v.f = f;
    unsigned int x = v.i;
    return (u16)((x + 0x7fffu + ((x >> 16) & 1u)) >> 16);   // RNE
}

// ---------------- f32 -> bf16 preconvert (weights, once per launch) -------
__global__ __launch_bounds__(256) void k_f2bf(
    const float* __restrict__ in, u16* __restrict__ out, int n)
{
    const int i = (blockIdx.x * 256 + threadIdx.x) * 4;
    if (i >= n) return;
    const float4 v = *(const float4*)(in + i);
    ushort4_t o;
    o.x = f2bf(v.x); o.y = f2bf(v.y); o.z = f2bf(v.z); o.w = f2bf(v.w);
    *(ushort4_t*)(out + i) = o;
}

// ---------------- gather + embedding + positional encoding ----------------
__global__ __launch_bounds__(256) void k_gather(
    const int* __restrict__ units, const int* __restrict__ paths,
    const float* __restrict__ emb, u16* __restrict__ x,
    int* __restrict__ tokout, int mode, int Bv)
{
    const int wave = threadIdx.x >> 6, lane = threadIdx.x & 63;
    const int t = blockIdx.x * 4 + wave;          // token row (l*Bv + b)
    const int l = t / Bv, b = t - l * Bv;
    int tokid;
    if (mode == 0) {
        const int d = l >> 4, u = l & 15;
        const int col = (b >> 6) * 32 + paths[d * 512 + b];
        tokid = units[u * 256 + col];
    } else {
        const int w = l >> 4, u = l & 15;
        tokid = units[u * 256 + b * 32 + w];
    }
    if (lane == 0) tokout[t] = tokid;
    const int c = lane * 4;
    const float4 e = *(const float4*)(emb + (size_t)tokid * H + c);
    const float i0 = (float)(c >> 1);
    const float a0 = (float)l * expf(-0.07195578415606394f * i0);
    const float a1 = (float)l * expf(-0.07195578415606394f * (i0 + 1.0f));
    ushort4_t o;
    o.x = f2bf(e.x + sinf(a0));
    o.y = f2bf(e.y + cosf(a0));
    o.z = f2bf(e.z + sinf(a1));
    o.w = f2bf(e.w + cosf(a1));
    *(ushort4_t*)(x + (size_t)t * H + c) = o;
}

// ---------------- MFMA GEMM, 128x256 tile: Y = X @ W^T + bias (opt ReLU) --
// 256 threads = 4 waves (2x2), wave tile 64x128 (acc 4x8). gload_lds width16,
// linear LDS dest + inverse-swizzled global source + swizzled ds_read.
// One buffer: X[128][32] (8 KB) + W[256][32] (16 KB) = 24 KB; dbuf 48 KB.
#define BUFW 12288       // u16 per buffer
__global__ __launch_bounds__(256) void k_gemm_mfma(
    const u16* __restrict__ X, const u16* __restrict__ W,
    const float* __restrict__ bias, u16* __restrict__ Y,
    int N, int K, int M, int relu)
{
    __shared__ __align__(16) u16 smem[2 * BUFW];   // 48 KB; epilogue reuse
    const int t = threadIdx.x;
    const int mtiles = M >> 8;
    const int nwg = gridDim.x;           // always divisible by 8 here
    const int bid = blockIdx.x;
    const int wg = (bid & 7) * (nwg >> 3) + (bid >> 3);   // XCD-chunked
    const int bm = (wg / mtiles) * 128;
    const int bn = (wg % mtiles) * 256;
    const int wave = t >> 6, lane = t & 63;
    const int wr = (wave >> 1) * 64;          // 0 / 64
    const int wc = (wave & 1) * 128;          // 0 / 128
    const int lrow = lane & 15;
    const int lg   = lane >> 4;

    // staging: 24 chunks of 16 rows (0-7: X rows, 8-23: W rows), 6 per wave
    const u16* gsrc[6]; int ldso[6];
    #pragma unroll
    for (int i = 0; i < 6; ++i) {
        const int c = wave * 6 + i;
        const int rr = lane >> 2;
        const int s  = lane & 3;
        if (c < 8) {
            const int r = c * 16 + rr;
            gsrc[i] = X + (size_t)(bm + r) * K + ((s ^ ((r >> 1) & 3)) * 8);
            ldso[i] = c * 512;
        } else {
            const int r = (c - 8) * 16 + rr;
            gsrc[i] = W + (size_t)(bn + r) * K + ((s ^ ((r >> 1) & 3)) * 8);
            ldso[i] = 4096 + (c - 8) * 512;
        }
    }
    // frag ds_read offsets (u16): row R, k-seg lg -> slot lg ^ ((R>>1)&3)
    int aoff[4], boff[8];
    #pragma unroll
    for (int m = 0; m < 4; ++m) {
        const int R = wr + m * 16 + lrow;
        aoff[m] = R * 32 + ((lg ^ ((R >> 1) & 3)) * 8);
    }
    #pragma unroll
    for (int n = 0; n < 8; ++n) {
        const int R = wc + n * 16 + lrow;
        boff[n] = 4096 + R * 32 + ((lg ^ ((R >> 1) & 3)) * 8);
    }

    f32x4 acc[4][8] = {};
    const int nt = K >> 5;

    #pragma unroll
    for (int i = 0; i < 6; ++i) {
        __builtin_amdgcn_global_load_lds(gsrc[i], &smem[ldso[i]], 16, 0, 0);
        gsrc[i] += 32;
    }
    __syncthreads();

    int cur = 0;
    for (int ts = 0; ts < nt; ++ts) {
        if (ts + 1 < nt) {
            const int nb = (cur ^ 1) * BUFW;
            #pragma unroll
            for (int i = 0; i < 6; ++i) {
                __builtin_amdgcn_global_load_lds(gsrc[i], &smem[nb + ldso[i]], 16, 0, 0);
                gsrc[i] += 32;
            }
        }
        const int cb = cur * BUFW;
        short8_t a[4], b[8];
        #pragma unroll
        for (int m = 0; m < 4; ++m) a[m] = *(const short8_t*)&smem[cb + aoff[m]];
        #pragma unroll
        for (int n = 0; n < 8; ++n) b[n] = *(const short8_t*)&smem[cb + boff[n]];
        #pragma unroll
        for (int m = 0; m < 4; ++m)
            #pragma unroll
            for (int n = 0; n < 8; ++n)
                acc[m][n] = __builtin_amdgcn_mfma_f32_16x16x32_bf16(
                    a[m], b[n], acc[m][n], 0, 0, 0);
        __syncthreads();     // drains gload_lds + guards buffer swap
        cur ^= 1;
    }

    // bias (C frag: col = lane&15, row = (lane>>4)*4 + j)
    float bv[8];
    #pragma unroll
    for (int n = 0; n < 8; ++n) bv[n] = bias[bn + wc + n * 16 + lrow];
    const int r0 = lg * 4;

    // epilogue via LDS, two 128-col halves; smem reused as [128][136]
    #pragma unroll
    for (int h = 0; h < 2; ++h) {
        if ((wave & 1) == h) {
            #pragma unroll
            for (int n = 0; n < 8; ++n) {
                const int lc = n * 16 + lrow;          // 0..127 within half
                #pragma unroll
                for (int m = 0; m < 4; ++m) {
                    const int lr = wr + m * 16 + r0;
                    #pragma unroll
                    for (int j = 0; j < 4; ++j) {
                        float v = acc[m][n][j] + bv[n];
                        if (relu) v = fmaxf(v, 0.f);
                        smem[(lr + j) * 136 + lc] = f2bf(v);
                    }
                }
            }
        }
        __syncthreads();
        #pragma unroll
        for (int it = 0; it < 8; ++it) {
            const int slot = it * 256 + t;     // 2048 slots = 128 rows x 16 segs
            const int row = slot >> 4;
            const int seg = (slot & 15) * 8;
            *(ushort8_t*)(Y + (size_t)(bm + row) * M + bn + h * 128 + seg) =
                *(const ushort8_t*)&smem[row * 136 + seg];
        }
        __syncthreads();
    }
}

// ---------------- MFMA flash attention (swapped-operand, online softmax) ---
__global__ __launch_bounds__(256) void k_attn_mfma(
    const u16* __restrict__ qkv, const int* __restrict__ tok,
    u16* __restrict__ out, int L, int Bv)
{
    __shared__ __align__(16) u16 Ks[128][40];
    __shared__ __align__(16) u16 Vt[32][136];
    __shared__ __align__(16) u16 Pl[128][136];
    __shared__ int msk[128];
    const int t = threadIdx.x;
    const int wave = t >> 6, lane = t & 63;
    const int lq = lane & 15, lg = lane >> 4;
    const int b = blockIdx.y >> 3, h = blockIdx.y & 7;
    const int q0 = blockIdx.x * 128 + wave * 32;
    const float scale = 0.17677669529663687f;

    short8_t qf[2];
    #pragma unroll
    for (int n = 0; n < 2; ++n)
        qf[n] = *(const short8_t*)(qkv +
            (size_t)((q0 + n * 16 + lq) * Bv + b) * 768 + h * DH + lg * 8);

    f32x4 o[2][2] = {};
    float mrun[2] = {-1e9f, -1e9f};
    float lrun[2] = {0.f, 0.f};

    for (int kt = 0; kt < L; kt += 128) {
        #pragma unroll
        for (int it = 0; it < 2; ++it) {
            const int slot = t + it * 256;
            const int row = slot >> 2;
            const int seg = (slot & 3) * 8;
            const u16* base = qkv + (size_t)((kt + row) * Bv + b) * 768 + 256 + h * DH + seg;
            *(ushort8_t*)&Ks[row][seg] = *(const ushort8_t*)base;
            const ushort8_t v8 = *(const ushort8_t*)(base + 256);
            #pragma unroll
            for (int e = 0; e < 8; ++e) Vt[seg + e][row] = v8[e];
        }
        if (t < 128) msk[t] = tok[(size_t)(kt + t) * Bv + b];
        __syncthreads();

        #pragma unroll
        for (int n = 0; n < 2; ++n) {
            f32x4 s[8];
            #pragma unroll
            for (int mp = 0; mp < 8; ++mp) {
                const short8_t kf = *(const short8_t*)&Ks[mp * 16 + lq][lg * 8];
                s[mp] = __builtin_amdgcn_mfma_f32_16x16x32_bf16(
                    kf, qf[n], (f32x4){0.f, 0.f, 0.f, 0.f}, 0, 0, 0);
            }
            float mx = -3.0e38f;
            #pragma unroll
            for (int mp = 0; mp < 8; ++mp) {
                #pragma unroll
                for (int j = 0; j < 4; ++j) {
                    float v = s[mp][j] * scale;
                    v = (msk[mp * 16 + lg * 4 + j] == 0) ? -1e9f : v;
                    s[mp][j] = v;
                    mx = fmaxf(mx, v);
                }
            }
            mx = fmaxf(mx, __shfl_xor(mx, 16));
            mx = fmaxf(mx, __shfl_xor(mx, 32));
            const float mnew = fmaxf(mrun[n], mx);
            const float fac = __expf(mrun[n] - mnew);
            mrun[n] = mnew;
            lrun[n] *= fac;
            #pragma unroll
            for (int dt = 0; dt < 2; ++dt)
                #pragma unroll
                for (int j = 0; j < 4; ++j) o[dt][n][j] *= fac;
            float lsum = 0.f;
            #pragma unroll
            for (int mp = 0; mp < 8; ++mp) {
                const float p0 = __expf(s[mp][0] - mnew);
                const float p1 = __expf(s[mp][1] - mnew);
                const float p2 = __expf(s[mp][2] - mnew);
                const float p3 = __expf(s[mp][3] - mnew);
                lsum += (p0 + p1) + (p2 + p3);
                uint2 pk;
                pk.x = (unsigned)f2bf(p0) | ((unsigned)f2bf(p1) << 16);
                pk.y = (unsigned)f2bf(p2) | ((unsigned)f2bf(p3) << 16);
                *(uint2*)&Pl[wave * 32 + n * 16 + lq][mp * 16 + lg * 4] = pk;
            }
            lsum += __shfl_xor(lsum, 16);
            lsum += __shfl_xor(lsum, 32);
            lrun[n] += lsum;
        }

        #pragma unroll
        for (int kk = 0; kk < 4; ++kk) {
            short8_t pf[2];
            #pragma unroll
            for (int n = 0; n < 2; ++n)
                pf[n] = *(const short8_t*)&Pl[wave * 32 + n * 16 + lq][kk * 32 + lg * 8];
            #pragma unroll
            for (int dt = 0; dt < 2; ++dt) {
                const short8_t vf = *(const short8_t*)&Vt[dt * 16 + lq][kk * 32 + lg * 8];
                #pragma unroll
                for (int n = 0; n < 2; ++n)
                    o[dt][n] = __builtin_amdgcn_mfma_f32_16x16x32_bf16(
                        vf, pf[n], o[dt][n], 0, 0, 0);
            }
        }
        __syncthreads();
    }

    #pragma unroll
    for (int n = 0; n < 2; ++n) {
        const float inv = 1.f / lrun[n];
        const int q = q0 + n * 16 + lq;
        u16* op = out + (size_t)(q * Bv + b) * H + h * DH;
        #pragma unroll
        for (int dt = 0; dt < 2; ++dt)
            #pragma unroll
            for (int j = 0; j < 4; ++j)
                op[dt * 16 + lg * 4 + j] = f2bf(o[dt][n][j] * inv);
    }
}

// ---------------- fused residual + LayerNorm (bf16 out, to ws) ------------
__global__ __launch_bounds__(256) void k_add_ln(
    const u16* __restrict__ x, const u16* __restrict__ r,
    const float* __restrict__ gs, const float* __restrict__ gb,
    u16* __restrict__ y)
{
    const int wave = threadIdx.x >> 6, lane = threadIdx.x & 63;
    const size_t row = (size_t)blockIdx.x * 4 + wave;
    const int c = lane * 4;
    const ushort4_t xv = *(const ushort4_t*)(x + row * H + c);
    const ushort4_t rv = *(const ushort4_t*)(r + row * H + c);
    float v[4] = { bf2f(xv.x) + bf2f(rv.x), bf2f(xv.y) + bf2f(rv.y),
                   bf2f(xv.z) + bf2f(rv.z), bf2f(xv.w) + bf2f(rv.w) };
    float sum = v[0] + v[1] + v[2] + v[3];
    float sq  = v[0]*v[0] + v[1]*v[1] + v[2]*v[2] + v[3]*v[3];
    #pragma unroll
    for (int off = 1; off < 64; off <<= 1) {
        sum += __shfl_xor(sum, off);
        sq  += __shfl_xor(sq, off);
    }
    const float mean = sum * (1.f / H);
    const float var  = sq * (1.f / H) - mean * mean;
    const float is   = rsqrtf(var + 1e-5f);
    const float4 sv = *(const float4*)(gs + c);
    const float4 bv = *(const float4*)(gb + c);
    ushort4_t o;
    o.x = f2bf((v[0] - mean) * is * sv.x + bv.x);
    o.y = f2bf((v[1] - mean) * is * sv.y + bv.y);
    o.z = f2bf((v[2] - mean) * is * sv.z + bv.z);
    o.w = f2bf((v[3] - mean) * is * sv.w + bv.w);
    *(ushort4_t*)(y + row * H + c) = o;
}

// ---------------- fused residual + LayerNorm (f32 out, to d_out) ----------
__global__ __launch_bounds__(256) void k_add_ln_f32(
    const u16* __restrict__ x, const u16* __restrict__ r,
    const float* __restrict__ gs, const float* __restrict__ gb,
    float* __restrict__ y)
{
    const int wave = threadIdx.x >> 6, lane = threadIdx.x & 63;
    const size_t row = (size_t)blockIdx.x * 4 + wave;
    const int c = lane * 4;
    const ushort4_t xv = *(const ushort4_t*)(x + row * H + c);
    const ushort4_t rv = *(const ushort4_t*)(r + row * H + c);
    float v[4] = { bf2f(xv.x) + bf2f(rv.x), bf2f(xv.y) + bf2f(rv.y),
                   bf2f(xv.z) + bf2f(rv.z), bf2f(xv.w) + bf2f(rv.w) };
    float sum = v[0] + v[1] + v[2] + v[3];
    float sq  = v[0]*v[0] + v[1]*v[1] + v[2]*v[2] + v[3]*v[3];
    #pragma unroll
    for (int off = 1; off < 64; off <<= 1) {
        sum += __shfl_xor(sum, off);
        sq  += __shfl_xor(sq, off);
    }
    const float mean = sum * (1.f / H);
    const float var  = sq * (1.f / H) - mean * mean;
    const float is   = rsqrtf(var + 1e-5f);
    const float4 sv = *(const float4*)(gs + c);
    const float4 bv = *(const float4*)(gb + c);
    float4 o;
    o.x = (v[0] - mean) * is * sv.x + bv.x;
    o.y = (v[1] - mean) * is * sv.y + bv.y;
    o.z = (v[2] - mean) * is * sv.z + bv.z;
    o.w = (v[3] - mean) * is * sv.w + bv.w;
    *(float4*)(y + row * H + c) = o;
}

// --------------------------------------------------------------------------
extern "C" void kernel_launch(void* const* d_in, const int* in_sizes, int n_in,
                              void* d_out, int out_size, void* d_ws, size_t ws_size,
                              hipStream_t stream)
{
    const int* units = (const int*)d_in[0];
    const int* paths = (const int*)d_in[1];
    const float* emb = (const float*)d_in[4];          // f32 inputs
    const float* const* ep = (const float* const*)(d_in + 5);
    const float* const* od = (const float* const*)(d_in + 17);
    float* out = (float*)d_out;                        // f32 output

    u16* bufX   = (u16*)d_ws;
    u16* bufBig = bufX + (size_t)N1 * H;
    u16* bufO   = bufBig + (size_t)N1 * FFDIM;
    int* tokb   = (int*)(bufO + (size_t)N1 * H);
    u16* wbuf   = (u16*)(tokb + N1);                   // bf16 weights, 6.3 MB

    const int wqkv = 2 * 768 * H, wout = 2 * H * H,
              wff1 = 2 * FFDIM * H, wff2 = 2 * H * FFDIM;
    const int encstride = wqkv + wout + wff1 + wff2;
    const float* const* encs[2] = { ep, od };
    for (int e = 0; e < 2; ++e) {
        u16* wb = wbuf + (size_t)e * encstride;
        const float* const* w = encs[e];
        k_f2bf<<<wqkv / 1024, 256, 0, stream>>>(w[0], wb, wqkv);
        k_f2bf<<<wout / 1024, 256, 0, stream>>>(w[2], wb + wqkv, wout);
        k_f2bf<<<wff1 / 1024, 256, 0, stream>>>(w[6], wb + wqkv + wout, wff1);
        k_f2bf<<<wff2 / 1024, 256, 0, stream>>>(w[8], wb + wqkv + wout + wff1, wff2);
    }

    auto run = [&](const float* const* w, const u16* wb, int L, int Bv, int mode, float* fin) {
        const int N = L * Bv;
        k_gather<<<N / 4, 256, 0, stream>>>(units, paths, emb, bufX, tokb, mode, Bv);
        for (int layer = 0; layer < 2; ++layer) {
            const u16* qkv_w = wb + (size_t)layer * 768 * H;
            const u16* out_w = wb + wqkv + (size_t)layer * H * H;
            const u16* ff1_w = wb + wqkv + wout + (size_t)layer * FFDIM * H;
            const u16* ff2_w = wb + wqkv + wout + wff1 + (size_t)layer * H * FFDIM;
            const float* qkv_b = w[1]  + (size_t)layer * 768;
            const float* out_b = w[3]  + (size_t)layer * H;
            const float* ln1s  = w[4]  + (size_t)layer * H;
            const float* ln1b  = w[5]  + (size_t)layer * H;
            const float* ff1b  = w[7]  + (size_t)layer * FFDIM;
            const float* ff2b  = w[9]  + (size_t)layer * H;
            const float* ln2s  = w[10] + (size_t)layer * H;
            const float* ln2b  = w[11] + (size_t)layer * H;

            // qkv projection (N x 768), 128x256 tiles
            k_gemm_mfma<<<(N/128)*(768/256), 256, 0, stream>>>(bufX, qkv_w, qkv_b, bufBig, N, H, 768, 0);
            // attention -> bufO
            k_attn_mfma<<<dim3(L/128, Bv*NH), 256, 0, stream>>>(bufBig, tokb, bufO, L, Bv);
            // out-proj (N x 256)
            k_gemm_mfma<<<(N/128)*(H/256), 256, 0, stream>>>(bufO, out_w, out_b, bufBig, N, H, H, 0);
            // x = LN(x + attnproj)
            k_add_ln<<<N/4, 256, 0, stream>>>(bufX, bufBig, ln1s, ln1b, bufX);
            // ff1 + relu (N x 1024)
            k_gemm_mfma<<<(N/128)*(FFDIM/256), 256, 0, stream>>>(bufX, ff1_w, ff1b, bufBig, N, H, FFDIM, 1);
            // ff2 (N x 256)
            k_gemm_mfma<<<(N/128)*(H/256), 256, 0, stream>>>(bufBig, ff2_w, ff2b, bufO, N, FFDIM, H, 0);
            if (layer == 1)
                k_add_ln_f32<<<N/4, 256, 0, stream>>>(bufX, bufO, ln2s, ln2b, fin);
            else
                k_add_ln<<<N/4, 256, 0, stream>>>(bufX, bufO, ln2s, ln2b, bufX);
        }
    };

    run(ep, wbuf, L1, B1, 0, out);                                   // expaths
    run(od, wbuf + (size_t)encstride, L2, B2, 1, out + (size_t)N1 * H); // order_enc
}

// Round 11
// 725.310 us; speedup vs baseline: 1.2960x; 1.2960x over previous
//
#include <hip/hip_runtime.h>
#include <math.h>

// Problem constants (fixed by setup_inputs: B=8, UPD=32, PPD=64)
#define H      256
#define NH     8
#define DH     32
#define FFDIM  1024
#define L1     128      // DEPTH*UNIT_LEN
#define B1     512      // B*PPD
#define L2     512      // UPD*UNIT_LEN
#define B2     8        // nb
#define N1     (L1*B1)  // 65536
#define N2     (L2*B2)  // 4096

typedef unsigned short u16;
typedef unsigned short ushort4_t __attribute__((ext_vector_type(4)));
typedef unsigned short ushort8_t __attribute__((ext_vector_type(8)));
typedef short          short8_t  __attribute__((ext_vector_type(8)));
typedef float          f32x4     __attribute__((ext_vector_type(4)));

__device__ __forceinline__ float bf2f(u16 u) {
    union { unsigned int i; float f; } v; v.i = ((unsigned int)u) << 16; return v.f;
}
__device__ __forceinline__ u16 f2bf(float f) {
    union { float f; unsigned int i; } v; v.f = f;
    unsigned int x = v.i;
    return (u16)((x + 0x7fffu + ((x >> 16) & 1u)) >> 16);   // RNE
}

// ---------------- f32 -> bf16 preconvert (weights, once per launch) -------
__global__ __launch_bounds__(256) void k_f2bf(
    const float* __restrict__ in, u16* __restrict__ out, int n)
{
    const int i = (blockIdx.x * 256 + threadIdx.x) * 4;
    if (i >= n) return;
    const float4 v = *(const float4*)(in + i);
    ushort4_t o;
    o.x = f2bf(v.x); o.y = f2bf(v.y); o.z = f2bf(v.z); o.w = f2bf(v.w);
    *(ushort4_t*)(out + i) = o;
}

// ---------------- gather + embedding + positional encoding ----------------
__global__ __launch_bounds__(256) void k_gather(
    const int* __restrict__ units, const int* __restrict__ paths,
    const float* __restrict__ emb, u16* __restrict__ x,
    int* __restrict__ tokout, int mode, int Bv)
{
    const int wave = threadIdx.x >> 6, lane = threadIdx.x & 63;
    const int t = blockIdx.x * 4 + wave;          // token row (l*Bv + b)
    const int l = t / Bv, b = t - l * Bv;
    int tokid;
    if (mode == 0) {
        const int d = l >> 4, u = l & 15;
        const int col = (b >> 6) * 32 + paths[d * 512 + b];
        tokid = units[u * 256 + col];
    } else {
        const int w = l >> 4, u = l & 15;
        tokid = units[u * 256 + b * 32 + w];
    }
    if (lane == 0) tokout[t] = tokid;
    const int c = lane * 4;
    const float4 e = *(const float4*)(emb + (size_t)tokid * H + c);
    const float i0 = (float)(c >> 1);
    const float a0 = (float)l * expf(-0.07195578415606394f * i0);
    const float a1 = (float)l * expf(-0.07195578415606394f * (i0 + 1.0f));
    ushort4_t o;
    o.x = f2bf(e.x + sinf(a0));
    o.y = f2bf(e.y + cosf(a0));
    o.z = f2bf(e.z + sinf(a1));
    o.w = f2bf(e.w + cosf(a1));
    *(ushort4_t*)(x + (size_t)t * H + c) = o;
}

// ---------------- MFMA GEMM 128x128 (round-8 geometry) --------------------
// 4-buffer, depth-3 prefetch, counted vmcnt + raw s_barrier (T4):
// loads never drain to 0 in the main loop. 4 gload_lds per wave per tile.
#define BUF_U16 8192      // one buffer: X[128][32] + W[128][32] = 16 KB
__global__ __launch_bounds__(256) void k_gemm_mfma(
    const u16* __restrict__ X, const u16* __restrict__ W,
    const float* __restrict__ bias, u16* __restrict__ Y,
    int N, int K, int M, int relu)
{
    __shared__ __align__(16) u16 smem[4 * BUF_U16];   // 64 KB; epilogue reuse
    const int t = threadIdx.x;
    const int mtiles = M >> 7;
    const int nwg = gridDim.x;           // always divisible by 8 here
    const int bid = blockIdx.x;
    const int wg = (bid & 7) * (nwg >> 3) + (bid >> 3);   // XCD-chunked
    const int bm = (wg / mtiles) * 128;
    const int bn = (wg % mtiles) * 128;
    const int wave = t >> 6, lane = t & 63;
    const int wr = (wave >> 1) * 64, wc = (wave & 1) * 64;
    const int lrow = lane & 15;
    const int lg   = lane >> 4;

    // staging: chunk c = wave*2+i covers LDS rows c*16..c*16+15 (linear dest,
    // inverse-swizzled global source; involution s ^= (row>>1)&3)
    const u16* gx[2]; const u16* gw[2];
    int ldsxo[2], ldswo[2];
    #pragma unroll
    for (int i = 0; i < 2; ++i) {
        const int c = wave * 2 + i;
        const int r = c * 16 + (lane >> 2);
        const int s = (lane & 3) ^ ((r >> 1) & 3);
        gx[i] = X + (size_t)(bm + r) * K + s * 8;
        gw[i] = W + (size_t)(bn + r) * K + s * 8;
        ldsxo[i] = c * 512;
        ldswo[i] = 4096 + c * 512;
    }
    // frag ds_read offsets (u16): row R, k-seg lg -> slot lg ^ ((R>>1)&3)
    int aoff[4], boff[4];
    #pragma unroll
    for (int m = 0; m < 4; ++m) {
        const int R = wr + m * 16 + lrow;
        aoff[m] = R * 32 + ((lg ^ ((R >> 1) & 3)) * 8);
    }
    #pragma unroll
    for (int n = 0; n < 4; ++n) {
        const int R = wc + n * 16 + lrow;
        boff[n] = 4096 + R * 32 + ((lg ^ ((R >> 1) & 3)) * 8);
    }

    f32x4 acc[4][4] = {};
    const int nt = K >> 5;    // >= 8 for all our K

#define STAGE(bufidx) do {                                                     \
    const int _nb = (bufidx) * BUF_U16;                                        \
    _Pragma("unroll")                                                          \
    for (int i = 0; i < 2; ++i) {                                              \
        __builtin_amdgcn_global_load_lds(gx[i], &smem[_nb + ldsxo[i]], 16, 0, 0); \
        __builtin_amdgcn_global_load_lds(gw[i], &smem[_nb + ldswo[i]], 16, 0, 0); \
        gx[i] += 32; gw[i] += 32;                                              \
    } } while (0)

#define COMPUTE(bufidx) do {                                                   \
    const int _cb = (bufidx) * BUF_U16;                                        \
    short8_t a[4], b[4];                                                       \
    _Pragma("unroll")                                                          \
    for (int m = 0; m < 4; ++m) a[m] = *(const short8_t*)&smem[_cb + aoff[m]]; \
    _Pragma("unroll")                                                          \
    for (int n = 0; n < 4; ++n) b[n] = *(const short8_t*)&smem[_cb + boff[n]]; \
    _Pragma("unroll")                                                          \
    for (int m = 0; m < 4; ++m)                                                \
        _Pragma("unroll")                                                      \
        for (int n = 0; n < 4; ++n)                                            \
            acc[m][n] = __builtin_amdgcn_mfma_f32_16x16x32_bf16(               \
                a[m], b[n], acc[m][n], 0, 0, 0);                               \
    } while (0)

    // prologue: stage tiles 0,1,2 (12 loads in flight per wave)
    STAGE(0); STAGE(1); STAGE(2);

    int cur = 0;
    for (int ts = 0; ts < nt - 3; ++ts) {
        STAGE((cur + 3) & 3);                     // tile ts+3
        asm volatile("s_waitcnt vmcnt(12)" ::: "memory");   // tile ts landed
        __builtin_amdgcn_s_barrier();
        COMPUTE(cur);
        __builtin_amdgcn_s_barrier();
        asm volatile("" ::: "memory");
        cur = (cur + 1) & 3;
    }
    // peeled tail: no more staging; drain 8 -> 4 -> 0
    asm volatile("s_waitcnt vmcnt(8)" ::: "memory");
    __builtin_amdgcn_s_barrier();
    COMPUTE(cur);
    __builtin_amdgcn_s_barrier();
    cur = (cur + 1) & 3;
    asm volatile("s_waitcnt vmcnt(4)" ::: "memory");
    __builtin_amdgcn_s_barrier();
    COMPUTE(cur);
    __builtin_amdgcn_s_barrier();
    cur = (cur + 1) & 3;
    asm volatile("s_waitcnt vmcnt(0)" ::: "memory");
    __builtin_amdgcn_s_barrier();
    COMPUTE(cur);
    __syncthreads();          // full drain before epilogue smem reuse

#undef STAGE
#undef COMPUTE

    // bias (C frag: col = lane&15, row = (lane>>4)*4 + j)
    float bv[4];
    #pragma unroll
    for (int n = 0; n < 4; ++n) bv[n] = bias[bn + wc + n * 16 + lrow];
    const int r0 = (lane >> 4) * 4;

    // epilogue via LDS, two 64-col halves; smem reused as [128][72]
    #pragma unroll
    for (int h = 0; h < 2; ++h) {
        if ((wave & 1) == h) {
            #pragma unroll
            for (int n = 0; n < 4; ++n) {
                const int lc = n * 16 + lrow;
                #pragma unroll
                for (int m = 0; m < 4; ++m) {
                    const int lr = wr + m * 16 + r0;
                    #pragma unroll
                    for (int j = 0; j < 4; ++j) {
                        float v = acc[m][n][j] + bv[n];
                        if (relu) v = fmaxf(v, 0.f);
                        smem[(lr + j) * 72 + lc] = f2bf(v);
                    }
                }
            }
        }
        __syncthreads();
        #pragma unroll
        for (int it = 0; it < 4; ++it) {
            const int slot = it * 256 + t;
            const int row = slot >> 3;
            const int seg = (slot & 7) * 8;
            *(ushort8_t*)(Y + (size_t)(bm + row) * M + bn + h * 64 + seg) =
                *(const ushort8_t*)&smem[row * 72 + seg];
        }
        __syncthreads();
    }
}

// ---------------- MFMA flash attention (swapped-operand, online softmax) ---
__global__ __launch_bounds__(256) void k_attn_mfma(
    const u16* __restrict__ qkv, const int* __restrict__ tok,
    u16* __restrict__ out, int L, int Bv)
{
    __shared__ __align__(16) u16 Ks[128][40];
    __shared__ __align__(16) u16 Vt[32][136];
    __shared__ __align__(16) u16 Pl[128][136];
    __shared__ int msk[128];
    const int t = threadIdx.x;
    const int wave = t >> 6, lane = t & 63;
    const int lq = lane & 15, lg = lane >> 4;
    const int b = blockIdx.y >> 3, h = blockIdx.y & 7;
    const int q0 = blockIdx.x * 128 + wave * 32;
    const float scale = 0.17677669529663687f;

    short8_t qf[2];
    #pragma unroll
    for (int n = 0; n < 2; ++n)
        qf[n] = *(const short8_t*)(qkv +
            (size_t)((q0 + n * 16 + lq) * Bv + b) * 768 + h * DH + lg * 8);

    f32x4 o[2][2] = {};
    float mrun[2] = {-1e9f, -1e9f};
    float lrun[2] = {0.f, 0.f};

    for (int kt = 0; kt < L; kt += 128) {
        #pragma unroll
        for (int it = 0; it < 2; ++it) {
            const int slot = t + it * 256;
            const int row = slot >> 2;
            const int seg = (slot & 3) * 8;
            const u16* base = qkv + (size_t)((kt + row) * Bv + b) * 768 + 256 + h * DH + seg;
            *(ushort8_t*)&Ks[row][seg] = *(const ushort8_t*)base;
            const ushort8_t v8 = *(const ushort8_t*)(base + 256);
            #pragma unroll
            for (int e = 0; e < 8; ++e) Vt[seg + e][row] = v8[e];
        }
        if (t < 128) msk[t] = tok[(size_t)(kt + t) * Bv + b];
        __syncthreads();

        #pragma unroll
        for (int n = 0; n < 2; ++n) {
            f32x4 s[8];
            #pragma unroll
            for (int mp = 0; mp < 8; ++mp) {
                const short8_t kf = *(const short8_t*)&Ks[mp * 16 + lq][lg * 8];
                s[mp] = __builtin_amdgcn_mfma_f32_16x16x32_bf16(
                    kf, qf[n], (f32x4){0.f, 0.f, 0.f, 0.f}, 0, 0, 0);
            }
            float mx = -3.0e38f;
            #pragma unroll
            for (int mp = 0; mp < 8; ++mp) {
                #pragma unroll
                for (int j = 0; j < 4; ++j) {
                    float v = s[mp][j] * scale;
                    v = (msk[mp * 16 + lg * 4 + j] == 0) ? -1e9f : v;
                    s[mp][j] = v;
                    mx = fmaxf(mx, v);
                }
            }
            mx = fmaxf(mx, __shfl_xor(mx, 16));
            mx = fmaxf(mx, __shfl_xor(mx, 32));
            const float mnew = fmaxf(mrun[n], mx);
            const float fac = __expf(mrun[n] - mnew);
            mrun[n] = mnew;
            lrun[n] *= fac;
            #pragma unroll
            for (int dt = 0; dt < 2; ++dt)
                #pragma unroll
                for (int j = 0; j < 4; ++j) o[dt][n][j] *= fac;
            float lsum = 0.f;
            #pragma unroll
            for (int mp = 0; mp < 8; ++mp) {
                const float p0 = __expf(s[mp][0] - mnew);
                const float p1 = __expf(s[mp][1] - mnew);
                const float p2 = __expf(s[mp][2] - mnew);
                const float p3 = __expf(s[mp][3] - mnew);
                lsum += (p0 + p1) + (p2 + p3);
                uint2 pk;
                pk.x = (unsigned)f2bf(p0) | ((unsigned)f2bf(p1) << 16);
                pk.y = (unsigned)f2bf(p2) | ((unsigned)f2bf(p3) << 16);
                *(uint2*)&Pl[wave * 32 + n * 16 + lq][mp * 16 + lg * 4] = pk;
            }
            lsum += __shfl_xor(lsum, 16);
            lsum += __shfl_xor(lsum, 32);
            lrun[n] += lsum;
        }

        #pragma unroll
        for (int kk = 0; kk < 4; ++kk) {
            short8_t pf[2];
            #pragma unroll
            for (int n = 0; n < 2; ++n)
                pf[n] = *(const short8_t*)&Pl[wave * 32 + n * 16 + lq][kk * 32 + lg * 8];
            #pragma unroll
            for (int dt = 0; dt < 2; ++dt) {
                const short8_t vf = *(const short8_t*)&Vt[dt * 16 + lq][kk * 32 + lg * 8];
                #pragma unroll
                for (int n = 0; n < 2; ++n)
                    o[dt][n] = __builtin_amdgcn_mfma_f32_16x16x32_bf16(
                        vf, pf[n], o[dt][n], 0, 0, 0);
            }
        }
        __syncthreads();
    }

    #pragma unroll
    for (int n = 0; n < 2; ++n) {
        const float inv = 1.f / lrun[n];
        const int q = q0 + n * 16 + lq;
        u16* op = out + (size_t)(q * Bv + b) * H + h * DH;
        #pragma unroll
        for (int dt = 0; dt < 2; ++dt)
            #pragma unroll
            for (int j = 0; j < 4; ++j)
                op[dt * 16 + lg * 4 + j] = f2bf(o[dt][n][j] * inv);
    }
}

// ---------------- fused residual + LayerNorm (bf16 out, to ws) ------------
__global__ __launch_bounds__(256) void k_add_ln(
    const u16* __restrict__ x, const u16* __restrict__ r,
    const float* __restrict__ gs, const float* __restrict__ gb,
    u16* __restrict__ y)
{
    const int wave = threadIdx.x >> 6, lane = threadIdx.x & 63;
    const size_t row = (size_t)blockIdx.x * 4 + wave;
    const int c = lane * 4;
    const ushort4_t xv = *(const ushort4_t*)(x + row * H + c);
    const ushort4_t rv = *(const ushort4_t*)(r + row * H + c);
    float v[4] = { bf2f(xv.x) + bf2f(rv.x), bf2f(xv.y) + bf2f(rv.y),
                   bf2f(xv.z) + bf2f(rv.z), bf2f(xv.w) + bf2f(rv.w) };
    float sum = v[0] + v[1] + v[2] + v[3];
    float sq  = v[0]*v[0] + v[1]*v[1] + v[2]*v[2] + v[3]*v[3];
    #pragma unroll
    for (int off = 1; off < 64; off <<= 1) {
        sum += __shfl_xor(sum, off);
        sq  += __shfl_xor(sq, off);
    }
    const float mean = sum * (1.f / H);
    const float var  = sq * (1.f / H) - mean * mean;
    const float is   = rsqrtf(var + 1e-5f);
    const float4 sv = *(const float4*)(gs + c);
    const float4 bv = *(const float4*)(gb + c);
    ushort4_t o;
    o.x = f2bf((v[0] - mean) * is * sv.x + bv.x);
    o.y = f2bf((v[1] - mean) * is * sv.y + bv.y);
    o.z = f2bf((v[2] - mean) * is * sv.z + bv.z);
    o.w = f2bf((v[3] - mean) * is * sv.w + bv.w);
    *(ushort4_t*)(y + row * H + c) = o;
}

// ---------------- fused residual + LayerNorm (f32 out, to d_out) ----------
__global__ __launch_bounds__(256) void k_add_ln_f32(
    const u16* __restrict__ x, const u16* __restrict__ r,
    const float* __restrict__ gs, const float* __restrict__ gb,
    float* __restrict__ y)
{
    const int wave = threadIdx.x >> 6, lane = threadIdx.x & 63;
    const size_t row = (size_t)blockIdx.x * 4 + wave;
    const int c = lane * 4;
    const ushort4_t xv = *(const ushort4_t*)(x + row * H + c);
    const ushort4_t rv = *(const ushort4_t*)(r + row * H + c);
    float v[4] = { bf2f(xv.x) + bf2f(rv.x), bf2f(xv.y) + bf2f(rv.y),
                   bf2f(xv.z) + bf2f(rv.z), bf2f(xv.w) + bf2f(rv.w) };
    float sum = v[0] + v[1] + v[2] + v[3];
    float sq  = v[0]*v[0] + v[1]*v[1] + v[2]*v[2] + v[3]*v[3];
    #pragma unroll
    for (int off = 1; off < 64; off <<= 1) {
        sum += __shfl_xor(sum, off);
        sq  += __shfl_xor(sq, off);
    }
    const float mean = sum * (1.f / H);
    const float var  = sq * (1.f / H) - mean * mean;
    const float is   = rsqrtf(var + 1e-5f);
    const float4 sv = *(const float4*)(gs + c);
    const float4 bv = *(const float4*)(gb + c);
    float4 o;
    o.x = (v[0] - mean) * is * sv.x + bv.x;
    o.y = (v[1] - mean) * is * sv.y + bv.y;
    o.z = (v[2] - mean) * is * sv.z + bv.z;
    o.w = (v[3] - mean) * is * sv.w + bv.w;
    *(float4*)(y + row * H + c) = o;
}

// --------------------------------------------------------------------------
extern "C" void kernel_launch(void* const* d_in, const int* in_sizes, int n_in,
                              void* d_out, int out_size, void* d_ws, size_t ws_size,
                              hipStream_t stream)
{
    const int* units = (const int*)d_in[0];
    const int* paths = (const int*)d_in[1];
    const float* emb = (const float*)d_in[4];          // f32 inputs
    const float* const* ep = (const float* const*)(d_in + 5);
    const float* const* od = (const float* const*)(d_in + 17);
    float* out = (float*)d_out;                        // f32 output

    u16* bufX   = (u16*)d_ws;
    u16* bufBig = bufX + (size_t)N1 * H;
    u16* bufO   = bufBig + (size_t)N1 * FFDIM;
    int* tokb   = (int*)(bufO + (size_t)N1 * H);
    u16* wbuf   = (u16*)(tokb + N1);                   // bf16 weights, 6.3 MB

    const int wqkv = 2 * 768 * H, wout = 2 * H * H,
              wff1 = 2 * FFDIM * H, wff2 = 2 * H * FFDIM;
    const int encstride = wqkv + wout + wff1 + wff2;
    const float* const* encs[2] = { ep, od };
    for (int e = 0; e < 2; ++e) {
        u16* wb = wbuf + (size_t)e * encstride;
        const float* const* w = encs[e];
        k_f2bf<<<wqkv / 1024, 256, 0, stream>>>(w[0], wb, wqkv);
        k_f2bf<<<wout / 1024, 256, 0, stream>>>(w[2], wb + wqkv, wout);
        k_f2bf<<<wff1 / 1024, 256, 0, stream>>>(w[6], wb + wqkv + wout, wff1);
        k_f2bf<<<wff2 / 1024, 256, 0, stream>>>(w[8], wb + wqkv + wout + wff1, wff2);
    }

    auto run = [&](const float* const* w, const u16* wb, int L, int Bv, int mode, float* fin) {
        const int N = L * Bv;
        k_gather<<<N / 4, 256, 0, stream>>>(units, paths, emb, bufX, tokb, mode, Bv);
        for (int layer = 0; layer < 2; ++layer) {
            const u16* qkv_w = wb + (size_t)layer * 768 * H;
            const u16* out_w = wb + wqkv + (size_t)layer * H * H;
            const u16* ff1_w = wb + wqkv + wout + (size_t)layer * FFDIM * H;
            const u16* ff2_w = wb + wqkv + wout + wff1 + (size_t)layer * H * FFDIM;
            const float* qkv_b = w[1]  + (size_t)layer * 768;
            const float* out_b = w[3]  + (size_t)layer * H;
            const float* ln1s  = w[4]  + (size_t)layer * H;
            const float* ln1b  = w[5]  + (size_t)layer * H;
            const float* ff1b  = w[7]  + (size_t)layer * FFDIM;
            const float* ff2b  = w[9]  + (size_t)layer * H;
            const float* ln2s  = w[10] + (size_t)layer * H;
            const float* ln2b  = w[11] + (size_t)layer * H;

            k_gemm_mfma<<<(N/128)*(768/128), 256, 0, stream>>>(bufX, qkv_w, qkv_b, bufBig, N, H, 768, 0);
            k_attn_mfma<<<dim3(L/128, Bv*NH), 256, 0, stream>>>(bufBig, tokb, bufO, L, Bv);
            k_gemm_mfma<<<(N/128)*(H/128), 256, 0, stream>>>(bufO, out_w, out_b, bufBig, N, H, H, 0);
            k_add_ln<<<N/4, 256, 0, stream>>>(bufX, bufBig, ln1s, ln1b, bufX);
            k_gemm_mfma<<<(N/128)*(FFDIM/128), 256, 0, stream>>>(bufX, ff1_w, ff1b, bufBig, N, H, FFDIM, 1);
            k_gemm_mfma<<<(N/128)*(H/128), 256, 0, stream>>>(bufBig, ff2_w, ff2b, bufO, N, FFDIM, H, 0);
            if (layer == 1)
                k_add_ln_f32<<<N/4, 256, 0, stream>>>(bufX, bufO, ln2s, ln2b, fin);
            else
                k_add_ln<<<N/4, 256, 0, stream>>>(bufX, bufO, ln2s, ln2b, bufX);
        }
    };

    run(ep, wbuf, L1, B1, 0, out);                                   // expaths
    run(od, wbuf + (size_t)encstride, L2, B2, 1, out + (size_t)N1 * H); // order_enc
}

// Round 12
// 595.944 us; speedup vs baseline: 1.5774x; 1.2171x over previous
//
#include <hip/hip_runtime.h>
#include <math.h>

// Problem constants (fixed by setup_inputs: B=8, UPD=32, PPD=64)
#define H      256
#define NH     8
#define DH     32
#define FFDIM  1024
#define L1     128      // DEPTH*UNIT_LEN
#define B1     512      // B*PPD
#define L2     512      // UPD*UNIT_LEN
#define B2     8        // nb
#define N1     (L1*B1)  // 65536
#define N2     (L2*B2)  // 4096
#define RT1    (N1/128) // 512 row tiles enc1
#define RT2    (N2/128) // 32 row tiles enc2

typedef unsigned short u16;
typedef unsigned short ushort4_t __attribute__((ext_vector_type(4)));
typedef unsigned short ushort8_t __attribute__((ext_vector_type(8)));
typedef short          short8_t  __attribute__((ext_vector_type(8)));
typedef float          f32x4     __attribute__((ext_vector_type(4)));

__device__ __forceinline__ float bf2f(u16 u) {
    union { unsigned int i; float f; } v; v.i = ((unsigned int)u) << 16; return v.f;
}
__device__ __forceinline__ u16 f2bf(float f) {
    union { float f; unsigned int i; } v; v.f = f;
    unsigned int x = v.i;
    return (u16)((x + 0x7fffu + ((x >> 16) & 1u)) >> 16);   // RNE
}

// ---------------- merged f32 -> bf16 weight preconvert (1 dispatch) -------
// segments (elems): e0:qkv 393216, out 131072, ff1 524288, ff2 524288; e1 same
__global__ __launch_bounds__(256) void k_f2bf8(
    const float* __restrict__ s0, const float* __restrict__ s1,
    const float* __restrict__ s2, const float* __restrict__ s3,
    const float* __restrict__ s4, const float* __restrict__ s5,
    const float* __restrict__ s6, const float* __restrict__ s7,
    u16* __restrict__ out)
{
    const int cums[9] = {0, 393216, 524288, 1048576, 1572864,
                         1966080, 2097152, 2621440, 3145728};
    const float* srcs[8] = {s0, s1, s2, s3, s4, s5, s6, s7};
    const int gbase = blockIdx.x * 1024;          // block-uniform segment
    int seg = 0;
    #pragma unroll
    for (int i = 1; i < 8; ++i) if (gbase >= cums[i]) seg = i;
    const int idx = gbase + threadIdx.x * 4;
    const float4 v = *(const float4*)(srcs[seg] + (idx - cums[seg]));
    ushort4_t o;
    o.x = f2bf(v.x); o.y = f2bf(v.y); o.z = f2bf(v.z); o.w = f2bf(v.w);
    *(ushort4_t*)(out + idx) = o;
}

// ---------------- merged gather + embedding + PE (both encoders) ----------
__global__ __launch_bounds__(256) void k_gather(
    const int* __restrict__ units, const int* __restrict__ paths,
    const float* __restrict__ emb,
    u16* __restrict__ x1, u16* __restrict__ x2,
    int* __restrict__ tokb1, int* __restrict__ tokb2)
{
    const int wave = threadIdx.x >> 6, lane = threadIdx.x & 63;
    const int t = blockIdx.x * 4 + wave;
    int tokid, l;
    u16* xp; int* tokp;
    if (t < N1) {                       // enc1: ctx gather
        l = t / B1; const int b = t - l * B1;
        const int d = l >> 4, u = l & 15;
        const int col = (b >> 6) * 32 + paths[d * 512 + b];
        tokid = units[u * 256 + col];
        xp = x1 + (size_t)t * H; tokp = tokb1 + t;
    } else {                            // enc2: order gather
        const int t2 = t - N1;
        l = t2 / B2; const int b = t2 - l * B2;
        const int w = l >> 4, u = l & 15;
        tokid = units[u * 256 + b * 32 + w];
        xp = x2 + (size_t)t2 * H; tokp = tokb2 + t2;
    }
    if (lane == 0) *tokp = tokid;
    const int c = lane * 4;
    const float4 e = *(const float4*)(emb + (size_t)tokid * H + c);
    const float i0 = (float)(c >> 1);
    const float a0 = (float)l * expf(-0.07195578415606394f * i0);
    const float a1 = (float)l * expf(-0.07195578415606394f * (i0 + 1.0f));
    ushort4_t o;
    o.x = f2bf(e.x + sinf(a0));
    o.y = f2bf(e.y + cosf(a0));
    o.z = f2bf(e.z + sinf(a1));
    o.w = f2bf(e.w + cosf(a1));
    *(ushort4_t*)(xp + c) = o;
}

// ---------------- MFMA GEMM 128x128 (round-8 core), merged encoders -------
// 2-buffer dbuf, gload_lds width16, linear dest + inv-swizzled source +
// swizzled ds_read. Row-tiles [0,RT1) -> enc1, [RT1,RT1+RT2) -> enc2.
#define BUF_U16 8192      // one buffer: X[128][32] + W[128][32] = 16 KB
__global__ __launch_bounds__(256) void k_gemm_mfma(
    const u16* __restrict__ X1, const u16* __restrict__ X2,
    const u16* __restrict__ W1, const u16* __restrict__ W2,
    const float* __restrict__ b1, const float* __restrict__ b2,
    u16* __restrict__ Y1, u16* __restrict__ Y2,
    int K, int M, int relu)
{
    __shared__ __align__(16) u16 smem[2 * BUF_U16];
    const int t = threadIdx.x;
    const int mtiles = M >> 7;
    const int nwg = gridDim.x;           // divisible by 8 (544*mtiles)
    const int bid = blockIdx.x;
    const int wg = (bid & 7) * (nwg >> 3) + (bid >> 3);   // XCD-chunked
    const int rt = wg / mtiles;
    const int bn = (wg % mtiles) * 128;
    const u16* X; const u16* W; const float* bias; u16* Y; int bm;
    if (rt < RT1) { X = X1; W = W1; bias = b1; Y = Y1; bm = rt * 128; }
    else          { X = X2; W = W2; bias = b2; Y = Y2; bm = (rt - RT1) * 128; }
    const int wave = t >> 6, lane = t & 63;
    const int wr = (wave >> 1) * 64, wc = (wave & 1) * 64;
    const int lrow = lane & 15;
    const int lg   = lane >> 4;

    const u16* gx[2]; const u16* gw[2];
    int ldsxo[2], ldswo[2];
    #pragma unroll
    for (int i = 0; i < 2; ++i) {
        const int c = wave * 2 + i;
        const int r = c * 16 + (lane >> 2);
        const int s = (lane & 3) ^ ((r >> 1) & 3);
        gx[i] = X + (size_t)(bm + r) * K + s * 8;
        gw[i] = W + (size_t)(bn + r) * K + s * 8;
        ldsxo[i] = c * 512;
        ldswo[i] = 4096 + c * 512;
    }
    int aoff[4], boff[4];
    #pragma unroll
    for (int m = 0; m < 4; ++m) {
        const int R = wr + m * 16 + lrow;
        aoff[m] = R * 32 + ((lg ^ ((R >> 1) & 3)) * 8);
    }
    #pragma unroll
    for (int n = 0; n < 4; ++n) {
        const int R = wc + n * 16 + lrow;
        boff[n] = 4096 + R * 32 + ((lg ^ ((R >> 1) & 3)) * 8);
    }

    f32x4 acc[4][4] = {};
    const int nt = K >> 5;

    #pragma unroll
    for (int i = 0; i < 2; ++i) {
        __builtin_amdgcn_global_load_lds(gx[i], &smem[ldsxo[i]], 16, 0, 0);
        __builtin_amdgcn_global_load_lds(gw[i], &smem[ldswo[i]], 16, 0, 0);
        gx[i] += 32; gw[i] += 32;
    }
    __syncthreads();

    int cur = 0;
    for (int ts = 0; ts < nt; ++ts) {
        if (ts + 1 < nt) {
            const int nb = (cur ^ 1) * BUF_U16;
            #pragma unroll
            for (int i = 0; i < 2; ++i) {
                __builtin_amdgcn_global_load_lds(gx[i], &smem[nb + ldsxo[i]], 16, 0, 0);
                __builtin_amdgcn_global_load_lds(gw[i], &smem[nb + ldswo[i]], 16, 0, 0);
                gx[i] += 32; gw[i] += 32;
            }
        }
        const int cb = cur * BUF_U16;
        short8_t a[4], b[4];
        #pragma unroll
        for (int m = 0; m < 4; ++m) a[m] = *(const short8_t*)&smem[cb + aoff[m]];
        #pragma unroll
        for (int n = 0; n < 4; ++n) b[n] = *(const short8_t*)&smem[cb + boff[n]];
        #pragma unroll
        for (int m = 0; m < 4; ++m)
            #pragma unroll
            for (int n = 0; n < 4; ++n)
                acc[m][n] = __builtin_amdgcn_mfma_f32_16x16x32_bf16(
                    a[m], b[n], acc[m][n], 0, 0, 0);
        __syncthreads();
        cur ^= 1;
    }

    float bv[4];
    #pragma unroll
    for (int n = 0; n < 4; ++n) bv[n] = bias[bn + wc + n * 16 + lrow];
    const int r0 = (lane >> 4) * 4;

    #pragma unroll
    for (int h = 0; h < 2; ++h) {
        if ((wave & 1) == h) {
            #pragma unroll
            for (int n = 0; n < 4; ++n) {
                const int lc = n * 16 + lrow;
                #pragma unroll
                for (int m = 0; m < 4; ++m) {
                    const int lr = wr + m * 16 + r0;
                    #pragma unroll
                    for (int j = 0; j < 4; ++j) {
                        float v = acc[m][n][j] + bv[n];
                        if (relu) v = fmaxf(v, 0.f);
                        smem[(lr + j) * 72 + lc] = f2bf(v);
                    }
                }
            }
        }
        __syncthreads();
        #pragma unroll
        for (int it = 0; it < 4; ++it) {
            const int slot = it * 256 + t;
            const int row = slot >> 3;
            const int seg = (slot & 7) * 8;
            *(ushort8_t*)(Y + (size_t)(bm + row) * M + bn + h * 64 + seg) =
                *(const ushort8_t*)&smem[row * 72 + seg];
        }
        __syncthreads();
    }
}

// ---------------- MFMA flash attention, merged encoders -------------------
// blocks [0,4096): enc1 (1 qtile x 4096 bh); [4096,4352): enc2 (4 x 64)
__global__ __launch_bounds__(256) void k_attn_mfma(
    const u16* __restrict__ qkv1, const u16* __restrict__ qkv2,
    const int* __restrict__ tok1, const int* __restrict__ tok2,
    u16* __restrict__ out1, u16* __restrict__ out2)
{
    __shared__ __align__(16) u16 Ks[128][40];
    __shared__ __align__(16) u16 Vt[32][136];
    __shared__ __align__(16) u16 Pl[128][136];
    __shared__ int msk[128];
    const int t = threadIdx.x;
    const int wave = t >> 6, lane = t & 63;
    const int lq = lane & 15, lg = lane >> 4;
    const int bid = blockIdx.x;
    const u16* qkv; const int* tok; u16* out;
    int L, Bv, b, h, qt;
    if (bid < B1 * NH) {
        qkv = qkv1; tok = tok1; out = out1; L = L1; Bv = B1;
        qt = 0; b = bid >> 3; h = bid & 7;
    } else {
        const int r = bid - B1 * NH;
        qkv = qkv2; tok = tok2; out = out2; L = L2; Bv = B2;
        qt = r >> 6; const int bh = r & 63; b = bh >> 3; h = bh & 7;
    }
    const int q0 = qt * 128 + wave * 32;
    const float scale = 0.17677669529663687f;

    short8_t qf[2];
    #pragma unroll
    for (int n = 0; n < 2; ++n)
        qf[n] = *(const short8_t*)(qkv +
            (size_t)((q0 + n * 16 + lq) * Bv + b) * 768 + h * DH + lg * 8);

    f32x4 o[2][2] = {};
    float mrun[2] = {-1e9f, -1e9f};
    float lrun[2] = {0.f, 0.f};

    for (int kt = 0; kt < L; kt += 128) {
        #pragma unroll
        for (int it = 0; it < 2; ++it) {
            const int slot = t + it * 256;
            const int row = slot >> 2;
            const int seg = (slot & 3) * 8;
            const u16* base = qkv + (size_t)((kt + row) * Bv + b) * 768 + 256 + h * DH + seg;
            *(ushort8_t*)&Ks[row][seg] = *(const ushort8_t*)base;
            const ushort8_t v8 = *(const ushort8_t*)(base + 256);
            #pragma unroll
            for (int e = 0; e < 8; ++e) Vt[seg + e][row] = v8[e];
        }
        if (t < 128) msk[t] = tok[(size_t)(kt + t) * Bv + b];
        __syncthreads();

        #pragma unroll
        for (int n = 0; n < 2; ++n) {
            f32x4 s[8];
            #pragma unroll
            for (int mp = 0; mp < 8; ++mp) {
                const short8_t kf = *(const short8_t*)&Ks[mp * 16 + lq][lg * 8];
                s[mp] = __builtin_amdgcn_mfma_f32_16x16x32_bf16(
                    kf, qf[n], (f32x4){0.f, 0.f, 0.f, 0.f}, 0, 0, 0);
            }
            float mx = -3.0e38f;
            #pragma unroll
            for (int mp = 0; mp < 8; ++mp) {
                #pragma unroll
                for (int j = 0; j < 4; ++j) {
                    float v = s[mp][j] * scale;
                    v = (msk[mp * 16 + lg * 4 + j] == 0) ? -1e9f : v;
                    s[mp][j] = v;
                    mx = fmaxf(mx, v);
                }
            }
            mx = fmaxf(mx, __shfl_xor(mx, 16));
            mx = fmaxf(mx, __shfl_xor(mx, 32));
            const float mnew = fmaxf(mrun[n], mx);
            const float fac = __expf(mrun[n] - mnew);
            mrun[n] = mnew;
            lrun[n] *= fac;
            #pragma unroll
            for (int dt = 0; dt < 2; ++dt)
                #pragma unroll
                for (int j = 0; j < 4; ++j) o[dt][n][j] *= fac;
            float lsum = 0.f;
            #pragma unroll
            for (int mp = 0; mp < 8; ++mp) {
                const float p0 = __expf(s[mp][0] - mnew);
                const float p1 = __expf(s[mp][1] - mnew);
                const float p2 = __expf(s[mp][2] - mnew);
                const float p3 = __expf(s[mp][3] - mnew);
                lsum += (p0 + p1) + (p2 + p3);
                uint2 pk;
                pk.x = (unsigned)f2bf(p0) | ((unsigned)f2bf(p1) << 16);
                pk.y = (unsigned)f2bf(p2) | ((unsigned)f2bf(p3) << 16);
                *(uint2*)&Pl[wave * 32 + n * 16 + lq][mp * 16 + lg * 4] = pk;
            }
            lsum += __shfl_xor(lsum, 16);
            lsum += __shfl_xor(lsum, 32);
            lrun[n] += lsum;
        }

        #pragma unroll
        for (int kk = 0; kk < 4; ++kk) {
            short8_t pf[2];
            #pragma unroll
            for (int n = 0; n < 2; ++n)
                pf[n] = *(const short8_t*)&Pl[wave * 32 + n * 16 + lq][kk * 32 + lg * 8];
            #pragma unroll
            for (int dt = 0; dt < 2; ++dt) {
                const short8_t vf = *(const short8_t*)&Vt[dt * 16 + lq][kk * 32 + lg * 8];
                #pragma unroll
                for (int n = 0; n < 2; ++n)
                    o[dt][n] = __builtin_amdgcn_mfma_f32_16x16x32_bf16(
                        vf, pf[n], o[dt][n], 0, 0, 0);
            }
        }
        __syncthreads();
    }

    #pragma unroll
    for (int n = 0; n < 2; ++n) {
        const float inv = 1.f / lrun[n];
        const int q = q0 + n * 16 + lq;
        u16* op = out + (size_t)(q * Bv + b) * H + h * DH;
        #pragma unroll
        for (int dt = 0; dt < 2; ++dt)
            #pragma unroll
            for (int j = 0; j < 4; ++j)
                op[dt * 16 + lg * 4 + j] = f2bf(o[dt][n][j] * inv);
    }
}

// ---------------- merged residual + LayerNorm (bf16 out, to ws) -----------
__global__ __launch_bounds__(256) void k_add_ln(
    const u16* __restrict__ x1, const u16* __restrict__ x2,
    const u16* __restrict__ r1, const u16* __restrict__ r2,
    const float* __restrict__ gs1, const float* __restrict__ gs2,
    const float* __restrict__ gb1, const float* __restrict__ gb2,
    u16* __restrict__ y1, u16* __restrict__ y2)
{
    const int wave = threadIdx.x >> 6, lane = threadIdx.x & 63;
    size_t row = (size_t)blockIdx.x * 4 + wave;
    const u16 *x, *r; const float *gs, *gb; u16* y;
    if (row < N1) { x = x1; r = r1; gs = gs1; gb = gb1; y = y1; }
    else { row -= N1; x = x2; r = r2; gs = gs2; gb = gb2; y = y2; }
    const int c = lane * 4;
    const ushort4_t xv = *(const ushort4_t*)(x + row * H + c);
    const ushort4_t rv = *(const ushort4_t*)(r + row * H + c);
    float v[4] = { bf2f(xv.x) + bf2f(rv.x), bf2f(xv.y) + bf2f(rv.y),
                   bf2f(xv.z) + bf2f(rv.z), bf2f(xv.w) + bf2f(rv.w) };
    float sum = v[0] + v[1] + v[2] + v[3];
    float sq  = v[0]*v[0] + v[1]*v[1] + v[2]*v[2] + v[3]*v[3];
    #pragma unroll
    for (int off = 1; off < 64; off <<= 1) {
        sum += __shfl_xor(sum, off);
        sq  += __shfl_xor(sq, off);
    }
    const float mean = sum * (1.f / H);
    const float var  = sq * (1.f / H) - mean * mean;
    const float is   = rsqrtf(var + 1e-5f);
    const float4 sv = *(const float4*)(gs + c);
    const float4 bv = *(const float4*)(gb + c);
    ushort4_t o;
    o.x = f2bf((v[0] - mean) * is * sv.x + bv.x);
    o.y = f2bf((v[1] - mean) * is * sv.y + bv.y);
    o.z = f2bf((v[2] - mean) * is * sv.z + bv.z);
    o.w = f2bf((v[3] - mean) * is * sv.w + bv.w);
    *(ushort4_t*)(y + row * H + c) = o;
}

// ---------------- merged residual + LayerNorm (f32 out, to d_out) ---------
// d_out is contiguous: enc1 rows [0,N1), enc2 rows [N1,N1+N2)
__global__ __launch_bounds__(256) void k_add_ln_f32(
    const u16* __restrict__ x1, const u16* __restrict__ x2,
    const u16* __restrict__ r1, const u16* __restrict__ r2,
    const float* __restrict__ gs1, const float* __restrict__ gs2,
    const float* __restrict__ gb1, const float* __restrict__ gb2,
    float* __restrict__ y)
{
    const int wave = threadIdx.x >> 6, lane = threadIdx.x & 63;
    const size_t grow = (size_t)blockIdx.x * 4 + wave;
    const int c = lane * 4;
    float* yp = y + grow * H + c;
    size_t row = grow;
    const u16 *x, *r; const float *gs, *gb;
    if (row < N1) { x = x1; r = r1; gs = gs1; gb = gb1; }
    else { row -= N1; x = x2; r = r2; gs = gs2; gb = gb2; }
    const ushort4_t xv = *(const ushort4_t*)(x + row * H + c);
    const ushort4_t rv = *(const ushort4_t*)(r + row * H + c);
    float v[4] = { bf2f(xv.x) + bf2f(rv.x), bf2f(xv.y) + bf2f(rv.y),
                   bf2f(xv.z) + bf2f(rv.z), bf2f(xv.w) + bf2f(rv.w) };
    float sum = v[0] + v[1] + v[2] + v[3];
    float sq  = v[0]*v[0] + v[1]*v[1] + v[2]*v[2] + v[3]*v[3];
    #pragma unroll
    for (int off = 1; off < 64; off <<= 1) {
        sum += __shfl_xor(sum, off);
        sq  += __shfl_xor(sq, off);
    }
    const float mean = sum * (1.f / H);
    const float var  = sq * (1.f / H) - mean * mean;
    const float is   = rsqrtf(var + 1e-5f);
    const float4 sv = *(const float4*)(gs + c);
    const float4 bv = *(const float4*)(gb + c);
    float4 o;
    o.x = (v[0] - mean) * is * sv.x + bv.x;
    o.y = (v[1] - mean) * is * sv.y + bv.y;
    o.z = (v[2] - mean) * is * sv.z + bv.z;
    o.w = (v[3] - mean) * is * sv.w + bv.w;
    *(float4*)yp = o;
}

// --------------------------------------------------------------------------
extern "C" void kernel_launch(void* const* d_in, const int* in_sizes, int n_in,
                              void* d_out, int out_size, void* d_ws, size_t ws_size,
                              hipStream_t stream)
{
    const int* units = (const int*)d_in[0];
    const int* paths = (const int*)d_in[1];
    const float* emb = (const float*)d_in[4];          // f32 inputs
    const float* const* ep = (const float* const*)(d_in + 5);
    const float* const* od = (const float* const*)(d_in + 17);
    float* out = (float*)d_out;                        // f32 output

    // workspace (~220 MB): separate enc1/enc2 activations + bf16 weights
    u16* bufX1   = (u16*)d_ws;
    u16* bufX2   = bufX1 + (size_t)N1 * H;
    u16* bufBig1 = bufX2 + (size_t)N2 * H;
    u16* bufBig2 = bufBig1 + (size_t)N1 * FFDIM;
    u16* bufO1   = bufBig2 + (size_t)N2 * FFDIM;
    u16* bufO2   = bufO1 + (size_t)N1 * H;
    int* tokb1   = (int*)(bufO2 + (size_t)N2 * H);
    int* tokb2   = tokb1 + N1;
    u16* wbuf    = (u16*)(tokb2 + N2);                 // 2*encstride bf16

    const int wqkv = 2 * 768 * H, wout = 2 * H * H,
              wff1 = 2 * FFDIM * H, wff2 = 2 * H * FFDIM;
    const int encstride = wqkv + wout + wff1 + wff2;   // 1572864

    // one dispatch converts all 8 weight matrices (both encoders)
    k_f2bf8<<<(2 * encstride) / 1024, 256, 0, stream>>>(
        ep[0], ep[2], ep[6], ep[8], od[0], od[2], od[6], od[8], wbuf);

    // merged gather
    k_gather<<<(N1 + N2) / 4, 256, 0, stream>>>(units, paths, emb,
                                                bufX1, bufX2, tokb1, tokb2);

    for (int layer = 0; layer < 2; ++layer) {
        const u16* wb1 = wbuf;
        const u16* wb2 = wbuf + (size_t)encstride;
        const u16* qkvw1 = wb1 + (size_t)layer * 768 * H;
        const u16* qkvw2 = wb2 + (size_t)layer * 768 * H;
        const u16* outw1 = wb1 + wqkv + (size_t)layer * H * H;
        const u16* outw2 = wb2 + wqkv + (size_t)layer * H * H;
        const u16* ff1w1 = wb1 + wqkv + wout + (size_t)layer * FFDIM * H;
        const u16* ff1w2 = wb2 + wqkv + wout + (size_t)layer * FFDIM * H;
        const u16* ff2w1 = wb1 + wqkv + wout + wff1 + (size_t)layer * H * FFDIM;
        const u16* ff2w2 = wb2 + wqkv + wout + wff1 + (size_t)layer * H * FFDIM;
        const float* qkvb1 = ep[1] + (size_t)layer * 768;
        const float* qkvb2 = od[1] + (size_t)layer * 768;
        const float* outb1 = ep[3] + (size_t)layer * H;
        const float* outb2 = od[3] + (size_t)layer * H;
        const float* ln1s1 = ep[4] + (size_t)layer * H;
        const float* ln1s2 = od[4] + (size_t)layer * H;
        const float* ln1b1 = ep[5] + (size_t)layer * H;
        const float* ln1b2 = od[5] + (size_t)layer * H;
        const float* ff1b1 = ep[7] + (size_t)layer * FFDIM;
        const float* ff1b2 = od[7] + (size_t)layer * FFDIM;
        const float* ff2b1 = ep[9] + (size_t)layer * H;
        const float* ff2b2 = od[9] + (size_t)layer * H;
        const float* ln2s1 = ep[10] + (size_t)layer * H;
        const float* ln2s2 = od[10] + (size_t)layer * H;
        const float* ln2b1 = ep[11] + (size_t)layer * H;
        const float* ln2b2 = od[11] + (size_t)layer * H;

        // qkv projection (merged)
        k_gemm_mfma<<<(RT1 + RT2) * (768 / 128), 256, 0, stream>>>(
            bufX1, bufX2, qkvw1, qkvw2, qkvb1, qkvb2, bufBig1, bufBig2, H, 768, 0);
        // attention (merged)
        k_attn_mfma<<<B1 * NH + B2 * NH * (L2 / 128), 256, 0, stream>>>(
            bufBig1, bufBig2, tokb1, tokb2, bufO1, bufO2);
        // out-proj (merged)
        k_gemm_mfma<<<(RT1 + RT2) * (H / 128), 256, 0, stream>>>(
            bufO1, bufO2, outw1, outw2, outb1, outb2, bufBig1, bufBig2, H, H, 0);
        // x = LN(x + attnproj) (merged)
        k_add_ln<<<(N1 + N2) / 4, 256, 0, stream>>>(
            bufX1, bufX2, bufBig1, bufBig2, ln1s1, ln1s2, ln1b1, ln1b2, bufX1, bufX2);
        // ff1 + relu (merged)
        k_gemm_mfma<<<(RT1 + RT2) * (FFDIM / 128), 256, 0, stream>>>(
            bufX1, bufX2, ff1w1, ff1w2, ff1b1, ff1b2, bufBig1, bufBig2, H, FFDIM, 1);
        // ff2 (merged)
        k_gemm_mfma<<<(RT1 + RT2) * (H / 128), 256, 0, stream>>>(
            bufBig1, bufBig2, ff2w1, ff2w2, ff2b1, ff2b2, bufO1, bufO2, FFDIM, H, 0);
        // x = LN(x + ff)
        if (layer == 1)
            k_add_ln_f32<<<(N1 + N2) / 4, 256, 0, stream>>>(
                bufX1, bufX2, bufO1, bufO2, ln2s1, ln2s2, ln2b1, ln2b2, out);
        else
            k_add_ln<<<(N1 + N2) / 4, 256, 0, stream>>>(
                bufX1, bufX2, bufO1, bufO2, ln2s1, ln2s2, ln2b1, ln2b2, bufX1, bufX2);
    }
}